// Round 9
// baseline (621.681 us; speedup 1.0000x reference)
//
#include <hip/hip_runtime.h>

// SelfAttention (Transformer-XL style) on gfx950.
// conv(hidden)->bf16, GEMM1 (256x192, 3-phase, B=f32 qkv_w reg-staged), RoPE prep,
// flash attn (128-row blocks, dbuf K/V), GEMM2 (256x128, 2-phase, B=f32 dense_w).
// Weight f32->bf16 conversion fused into GEMM staging (saves ~65us of conv kernels).

typedef __attribute__((ext_vector_type(4))) float f32x4;
typedef __attribute__((ext_vector_type(8))) short bf16x8;
typedef unsigned short u16;

#define SQ   1024
#define BSZ  2
#define H    4096
#define NH   32
#define HD   128
#define MEML 1024
#define KV   2048

__device__ __forceinline__ u16 f32_to_bf16(float f) {
  union { float f; unsigned int u; } v; v.f = f;
  unsigned int r = v.u + 0x7FFFu + ((v.u >> 16) & 1u);
  return (u16)(r >> 16);
}
__device__ __forceinline__ float bf16_to_f32(u16 x) {
  union { unsigned int u; float f; } v; v.u = ((unsigned int)x) << 16; return v.f;
}

__device__ __forceinline__ void gload_lds16(const void* g, void* l) {
  __builtin_amdgcn_global_load_lds((const __attribute__((address_space(1))) void*)g,
                                   (__attribute__((address_space(3))) void*)l, 16, 0, 0);
}

// ---------------- f32 -> bf16 convert ----------------
__global__ __launch_bounds__(256) void conv_bf16(const float* __restrict__ in,
                                                 u16* __restrict__ out, int n4) {
  int idx = blockIdx.x * 256 + threadIdx.x;
  if (idx < n4) {
    float4 v = ((const float4*)in)[idx];
    ushort4 o;
    o.x = f32_to_bf16(v.x); o.y = f32_to_bf16(v.y);
    o.z = f32_to_bf16(v.z); o.w = f32_to_bf16(v.w);
    ((ushort4*)out)[idx] = o;
  }
}

// ---------------- RoPE tables ----------------
__global__ __launch_bounds__(256) void rope_tables(float* __restrict__ cost, float* __restrict__ sint) {
  int idx = blockIdx.x * 256 + threadIdx.x;   // 65536 = 1024 s * 64 j
  int s = idx >> 6, j = idx & 63;
  float inv = powf(10000.0f, -(float)j / 64.0f);
  float ang = (float)(MEML + s) * inv;
  cost[idx] = cosf(ang);
  sint[idx] = sinf(ang);
}

// ---------------- GEMM1: C[M,N](bf16) = A(bf16) * B(f32)^T + bias; 256x192, BK=64 ----
// 8 waves (2M x 4N), per-wave 128x48, acc[8][3]. 3 phases/K-tile, 16 MFMA each.
// B is f32: reg-load tile kt+2 at ph0, cvt+ds_write at ph2 (region free after ph1).
__global__ __launch_bounds__(512, 2) void gemm3p(const u16* __restrict__ A, const float* __restrict__ Bf,
                                                 const float* __restrict__ bias, u16* __restrict__ C,
                                                 int N, int K) {
  __shared__ char lds[2][57344];   // A: 4x8192 @0, B: 3x8192 @32768
  const int tid = threadIdx.x;
  const int lane = tid & 63;
  const int w = tid >> 6;
  const int wm = w >> 2, wn = w & 3;
  const int rl = lane & 15, cg = lane >> 4;
  const int m0 = blockIdx.y * 256, n0 = blockIdx.x * 192;
  const int nt = K >> 6;

  const int srow = tid >> 3;                              // 0..63 (unit-local row)
  const int cB = tid & 7;                                 // 16B chunk within row
  const int scb = (cB << 4) ^ ((srow & 7) << 4);          // pre-swizzled source byte col (A path)

  auto stage_a = [&](int tile, int ua) {
    if (tile >= nt) return;
    gload_lds16((const char*)(A + (size_t)(m0 + ua * 64 + srow) * K + (size_t)tile * 64) + scb,
                lds[tile & 1] + ua * 8192 + tid * 16);
  };
  // write 8 bf16 (from 2 float4) into swizzled B slot of unit u
  auto wrB = [&](char* bufb, int u, float4 lo, float4 hi) {
    union { bf16x8 v; u16 e[8]; } pk;
    pk.e[0] = f32_to_bf16(lo.x); pk.e[1] = f32_to_bf16(lo.y);
    pk.e[2] = f32_to_bf16(lo.z); pk.e[3] = f32_to_bf16(lo.w);
    pk.e[4] = f32_to_bf16(hi.x); pk.e[5] = f32_to_bf16(hi.y);
    pk.e[6] = f32_to_bf16(hi.z); pk.e[7] = f32_to_bf16(hi.w);
    *(bf16x8*)(bufb + 32768 + u * 8192 + srow * 128 + ((cB << 4) ^ ((srow & 7) << 4))) = pk.v;
  };

  f32x4 acc[8][3];
#pragma unroll
  for (int i = 0; i < 8; ++i)
#pragma unroll
    for (int j = 0; j < 3; ++j) acc[i][j] = (f32x4){0.f, 0.f, 0.f, 0.f};

  bf16x8 af0[4][2], af1[4][2], bf[3][2];

  auto read_am = [&](const char* buf, int mh, bf16x8 (&dst)[4][2]) {
#pragma unroll
    for (int mi = 0; mi < 4; ++mi) {
      int R = wm * 128 + mh * 64 + mi * 16 + rl;
#pragma unroll
      for (int kk = 0; kk < 2; ++kk) {
        int cb = (kk * 64 + cg * 16) ^ ((R & 7) << 4);
        dst[mi][kk] = *(const bf16x8*)(buf + R * 128 + cb);
      }
    }
  };
  auto read_b1 = [&](const char* buf, int nl) {
    int R = wn * 48 + nl * 16 + rl;
#pragma unroll
    for (int kk = 0; kk < 2; ++kk) {
      int cb = (kk * 64 + cg * 16) ^ ((R & 7) << 4);
      bf[nl][kk] = *(const bf16x8*)(buf + 32768 + R * 128 + cb);
    }
  };

  // prologue: A0 via gload_lds; B tiles 0,1 via reg-cvt path
#pragma unroll
  for (int u = 0; u < 4; ++u) stage_a(0, u);
#pragma unroll
  for (int t = 0; t < 2; ++t)
#pragma unroll
    for (int u = 0; u < 3; ++u) {
      const float* s = Bf + (size_t)(n0 + u * 64 + srow) * K + (size_t)t * 64 + cB * 8;
      float4 lo = ((const float4*)s)[0];
      float4 hi = ((const float4*)s)[1];
      wrB(lds[t], u, lo, hi);
    }
  asm volatile("s_waitcnt vmcnt(0) lgkmcnt(0)" ::: "memory");
  __builtin_amdgcn_s_barrier();

  for (int kt = 0; kt < nt; ++kt) {
    char* buf = lds[kt & 1];
    const bool pf = (kt + 2 < nt);
    // ---- ph0: issue B(kt+2) reg loads; read af0,b0,b1; stage A(kt+1) u0,u1 ----
    float4 rb[6];
    if (pf) {
#pragma unroll
      for (int u = 0; u < 3; ++u) {
        const float* s = Bf + (size_t)(n0 + u * 64 + srow) * K + (size_t)(kt + 2) * 64 + cB * 8;
        rb[u * 2]     = ((const float4*)s)[0];
        rb[u * 2 + 1] = ((const float4*)s)[1];
      }
    }
    read_am(buf, 0, af0);
    read_b1(buf, 0); read_b1(buf, 1);
    stage_a(kt + 1, 0); stage_a(kt + 1, 1);
    __builtin_amdgcn_s_barrier();
    asm volatile("s_waitcnt lgkmcnt(0)" ::: "memory");
    __builtin_amdgcn_s_setprio(1);
#pragma unroll
    for (int kk = 0; kk < 2; ++kk)
#pragma unroll
      for (int mi = 0; mi < 4; ++mi) {
        acc[mi][0] = __builtin_amdgcn_mfma_f32_16x16x32_bf16(af0[mi][kk], bf[0][kk], acc[mi][0], 0, 0, 0);
        acc[mi][1] = __builtin_amdgcn_mfma_f32_16x16x32_bf16(af0[mi][kk], bf[1][kk], acc[mi][1], 0, 0, 0);
      }
    __builtin_amdgcn_s_setprio(0);
    __builtin_amdgcn_s_barrier();
    // ---- ph1: read af1,b2; stage A(kt+1) u2,u3 ----
    read_am(buf, 1, af1);
    read_b1(buf, 2);
    stage_a(kt + 1, 2); stage_a(kt + 1, 3);
    __builtin_amdgcn_s_barrier();
    asm volatile("s_waitcnt lgkmcnt(0)" ::: "memory");
    __builtin_amdgcn_s_setprio(1);
#pragma unroll
    for (int kk = 0; kk < 2; ++kk)
#pragma unroll
      for (int mi = 0; mi < 4; ++mi) {
        acc[4 + mi][1] = __builtin_amdgcn_mfma_f32_16x16x32_bf16(af1[mi][kk], bf[1][kk], acc[4 + mi][1], 0, 0, 0);
        acc[4 + mi][2] = __builtin_amdgcn_mfma_f32_16x16x32_bf16(af1[mi][kk], bf[2][kk], acc[4 + mi][2], 0, 0, 0);
      }
    __builtin_amdgcn_s_setprio(0);
    __builtin_amdgcn_s_barrier();
    // ---- ph2: cvt+write B(kt+2) -> buf (B region free after ph1); mfma mh0xb2+mh1xb0 ----
    if (pf) {
#pragma unroll
      for (int u = 0; u < 3; ++u) wrB(buf, u, rb[u * 2], rb[u * 2 + 1]);
    }
    asm volatile("s_waitcnt lgkmcnt(0)" ::: "memory");
    __builtin_amdgcn_s_barrier();
    __builtin_amdgcn_s_setprio(1);
#pragma unroll
    for (int kk = 0; kk < 2; ++kk)
#pragma unroll
      for (int mi = 0; mi < 4; ++mi) {
        acc[mi][2] = __builtin_amdgcn_mfma_f32_16x16x32_bf16(af0[mi][kk], bf[2][kk], acc[mi][2], 0, 0, 0);
        acc[4 + mi][0] = __builtin_amdgcn_mfma_f32_16x16x32_bf16(af1[mi][kk], bf[0][kk], acc[4 + mi][0], 0, 0, 0);
      }
    __builtin_amdgcn_s_setprio(0);
    asm volatile("s_waitcnt vmcnt(0)" ::: "memory");   // A(kt+1) landed
    __builtin_amdgcn_s_barrier();
  }

  // epilogue: C layout col=lane&15, row=(lane>>4)*4+j
#pragma unroll
  for (int ni = 0; ni < 3; ++ni) {
    int col = n0 + wn * 48 + ni * 16 + rl;
    float bv = bias[col];
#pragma unroll
    for (int mi = 0; mi < 8; ++mi) {
      int rbase = m0 + wm * 128 + mi * 16 + cg * 4;
#pragma unroll
      for (int j = 0; j < 4; ++j)
        C[(size_t)(rbase + j) * N + col] = f32_to_bf16(acc[mi][ni][j] + bv);
    }
  }
}

// ---------------- GEMM2: C[M,N](f32) = A(bf16) * B(f32)^T + bias; 256x128, BK=64 ----
// 8 waves (2M x 4N), per-wave 128x32, acc[8][2]. 2 phases/K-tile, 16 MFMA each.
__global__ __launch_bounds__(512, 2) void gemm2p(const u16* __restrict__ A, const float* __restrict__ Bf,
                                                 const float* __restrict__ bias, float* __restrict__ C,
                                                 int N, int K) {
  __shared__ char lds[2][49152];   // A: 4x8192 @0, B: 2x8192 @32768
  const int tid = threadIdx.x;
  const int lane = tid & 63;
  const int w = tid >> 6;
  const int wm = w >> 2, wn = w & 3;
  const int rl = lane & 15, cg = lane >> 4;
  const int m0 = blockIdx.y * 256, n0 = blockIdx.x * 128;
  const int nt = K >> 6;

  const int srow = tid >> 3;
  const int cB = tid & 7;
  const int scb = (cB << 4) ^ ((srow & 7) << 4);

  auto stage_a = [&](int tile, int ua) {
    if (tile >= nt) return;
    gload_lds16((const char*)(A + (size_t)(m0 + ua * 64 + srow) * K + (size_t)tile * 64) + scb,
                lds[tile & 1] + ua * 8192 + tid * 16);
  };
  auto wrB = [&](char* bufb, int u, float4 lo, float4 hi) {
    union { bf16x8 v; u16 e[8]; } pk;
    pk.e[0] = f32_to_bf16(lo.x); pk.e[1] = f32_to_bf16(lo.y);
    pk.e[2] = f32_to_bf16(lo.z); pk.e[3] = f32_to_bf16(lo.w);
    pk.e[4] = f32_to_bf16(hi.x); pk.e[5] = f32_to_bf16(hi.y);
    pk.e[6] = f32_to_bf16(hi.z); pk.e[7] = f32_to_bf16(hi.w);
    *(bf16x8*)(bufb + 32768 + u * 8192 + srow * 128 + ((cB << 4) ^ ((srow & 7) << 4))) = pk.v;
  };

  f32x4 acc[8][2];
#pragma unroll
  for (int i = 0; i < 8; ++i)
#pragma unroll
    for (int j = 0; j < 2; ++j) acc[i][j] = (f32x4){0.f, 0.f, 0.f, 0.f};

  bf16x8 af0[4][2], af1[4][2], bf[2][2];

  auto read_am = [&](const char* buf, int mh, bf16x8 (&dst)[4][2]) {
#pragma unroll
    for (int mi = 0; mi < 4; ++mi) {
      int R = wm * 128 + mh * 64 + mi * 16 + rl;
#pragma unroll
      for (int kk = 0; kk < 2; ++kk) {
        int cb = (kk * 64 + cg * 16) ^ ((R & 7) << 4);
        dst[mi][kk] = *(const bf16x8*)(buf + R * 128 + cb);
      }
    }
  };
  auto read_b1 = [&](const char* buf, int nl) {
    int R = wn * 32 + nl * 16 + rl;
#pragma unroll
    for (int kk = 0; kk < 2; ++kk) {
      int cb = (kk * 64 + cg * 16) ^ ((R & 7) << 4);
      bf[nl][kk] = *(const bf16x8*)(buf + 32768 + R * 128 + cb);
    }
  };

  // prologue
#pragma unroll
  for (int u = 0; u < 4; ++u) stage_a(0, u);
#pragma unroll
  for (int t = 0; t < 2; ++t)
#pragma unroll
    for (int u = 0; u < 2; ++u) {
      const float* s = Bf + (size_t)(n0 + u * 64 + srow) * K + (size_t)t * 64 + cB * 8;
      float4 lo = ((const float4*)s)[0];
      float4 hi = ((const float4*)s)[1];
      wrB(lds[t], u, lo, hi);
    }
  asm volatile("s_waitcnt vmcnt(0) lgkmcnt(0)" ::: "memory");
  __builtin_amdgcn_s_barrier();

  for (int kt = 0; kt < nt; ++kt) {
    char* buf = lds[kt & 1];
    const bool pf = (kt + 2 < nt);
    // ---- ph0: issue B(kt+2) loads; read af0,b0,b1; stage A(kt+1) u0,u1 ----
    float4 rb[4];
    if (pf) {
#pragma unroll
      for (int u = 0; u < 2; ++u) {
        const float* s = Bf + (size_t)(n0 + u * 64 + srow) * K + (size_t)(kt + 2) * 64 + cB * 8;
        rb[u * 2]     = ((const float4*)s)[0];
        rb[u * 2 + 1] = ((const float4*)s)[1];
      }
    }
    read_am(buf, 0, af0);
    read_b1(buf, 0); read_b1(buf, 1);
    stage_a(kt + 1, 0); stage_a(kt + 1, 1);
    __builtin_amdgcn_s_barrier();
    asm volatile("s_waitcnt lgkmcnt(0)" ::: "memory");
    __builtin_amdgcn_s_setprio(1);
#pragma unroll
    for (int kk = 0; kk < 2; ++kk)
#pragma unroll
      for (int mi = 0; mi < 4; ++mi) {
        acc[mi][0] = __builtin_amdgcn_mfma_f32_16x16x32_bf16(af0[mi][kk], bf[0][kk], acc[mi][0], 0, 0, 0);
        acc[mi][1] = __builtin_amdgcn_mfma_f32_16x16x32_bf16(af0[mi][kk], bf[1][kk], acc[mi][1], 0, 0, 0);
      }
    __builtin_amdgcn_s_setprio(0);
    __builtin_amdgcn_s_barrier();
    // ---- ph1: read af1; stage A(kt+1) u2,u3; cvt+write B(kt+2) (free after ph0) ----
    read_am(buf, 1, af1);
    stage_a(kt + 1, 2); stage_a(kt + 1, 3);
    if (pf) { wrB(buf, 0, rb[0], rb[1]); wrB(buf, 1, rb[2], rb[3]); }
    __builtin_amdgcn_s_barrier();
    asm volatile("s_waitcnt lgkmcnt(0)" ::: "memory");
    __builtin_amdgcn_s_setprio(1);
#pragma unroll
    for (int kk = 0; kk < 2; ++kk)
#pragma unroll
      for (int mi = 0; mi < 4; ++mi) {
        acc[4 + mi][0] = __builtin_amdgcn_mfma_f32_16x16x32_bf16(af1[mi][kk], bf[0][kk], acc[4 + mi][0], 0, 0, 0);
        acc[4 + mi][1] = __builtin_amdgcn_mfma_f32_16x16x32_bf16(af1[mi][kk], bf[1][kk], acc[4 + mi][1], 0, 0, 0);
      }
    __builtin_amdgcn_s_setprio(0);
    asm volatile("s_waitcnt vmcnt(0)" ::: "memory");   // A(kt+1) landed
    __builtin_amdgcn_s_barrier();
  }

  // epilogue
#pragma unroll
  for (int ni = 0; ni < 2; ++ni) {
    int col = n0 + wn * 32 + ni * 16 + rl;
    float bv = bias[col];
#pragma unroll
    for (int mi = 0; mi < 8; ++mi) {
      int rbase = m0 + wm * 128 + mi * 16 + cg * 4;
#pragma unroll
      for (int j = 0; j < 4; ++j)
        C[(size_t)(rbase + j) * N + col] = acc[mi][ni][j] + bv;
    }
  }
}

// ---------------- prep: roped Q (scaled) and roped new-K (mixed is bf16) ----------
__global__ __launch_bounds__(256) void prep_qk(const u16* __restrict__ mixed,
                                               const float* __restrict__ cost,
                                               const float* __restrict__ sint,
                                               u16* __restrict__ Qb, u16* __restrict__ Kb) {
  int s0 = blockIdx.x * 64, head = blockIdx.y;
  int b = head >> 5, nh = head & 31;
  int tid = threadIdx.x;
  const float qs = 0.08838834764831845f;  // 1/sqrt(128)
#pragma unroll
  for (int i = 0; i < 16; ++i) {
    int flat = i * 256 + tid;    // 4096 = 64 s * 64 j
    int sl = flat >> 6, j = flat & 63;
    int s = s0 + sl;
    size_t base = ((size_t)(s * 2 + b)) * 12288 + (size_t)nh * 384;
    float q1 = bf16_to_f32(mixed[base + j]),       q2 = bf16_to_f32(mixed[base + j + 64]);
    float k1 = bf16_to_f32(mixed[base + 128 + j]), k2 = bf16_to_f32(mixed[base + 192 + j]);
    float c = cost[s * 64 + j], sn = sint[s * 64 + j];
    float q1r = q1 * c - q2 * sn, q2r = q2 * c + q1 * sn;
    float k1r = k1 * c - k2 * sn, k2r = k2 * c + k1 * sn;
    size_t qoff = ((size_t)head * SQ + s) * HD;
    Qb[qoff + j]      = f32_to_bf16(q1r * qs);
    Qb[qoff + j + 64] = f32_to_bf16(q2r * qs);
    size_t koff = ((size_t)head * KV + MEML + s) * HD;
    Kb[koff + j]      = f32_to_bf16(k1r);
    Kb[koff + j + 64] = f32_to_bf16(k2r);
  }
}

// ---------------- prep: mem-K copy + V transposed per head ----------------
__global__ __launch_bounds__(256) void prep_kv(const u16* __restrict__ mixed,
                                               const float* __restrict__ mem,
                                               u16* __restrict__ Kb, u16* __restrict__ Vtb) {
  int t0 = blockIdx.x * 64, head = blockIdx.y;
  int b = head >> 5, nh = head & 31;
  __shared__ u16 vt[128 * 72];
  int tid = threadIdx.x;
  if (t0 < MEML) {
#pragma unroll
    for (int i = 0; i < 32; ++i) {
      int flat = i * 256 + tid;
      int tl = flat >> 7, d = flat & 127;
      float kvv = mem[((size_t)b * MEML + t0 + tl) * 8192 + (size_t)nh * HD + d];
      Kb[((size_t)head * KV + t0 + tl) * HD + d] = f32_to_bf16(kvv);
    }
  }
#pragma unroll
  for (int i = 0; i < 32; ++i) {
    int flat = i * 256 + tid;
    int tl = flat >> 7, d = flat & 127;
    int t = t0 + tl;
    u16 v;
    if (t < MEML) v = f32_to_bf16(mem[((size_t)b * MEML + t) * 8192 + 4096 + (size_t)nh * HD + d]);
    else          v = mixed[((size_t)((t - MEML) * 2 + b)) * 12288 + (size_t)nh * 384 + 256 + d];
    vt[d * 72 + tl] = v;
  }
  __syncthreads();
#pragma unroll
  for (int i = 0; i < 4; ++i) {
    int c = i * 256 + tid;
    int d = c >> 3, slot = c & 7;
    *(bf16x8*)(Vtb + ((size_t)head * HD + d) * KV + t0 + slot * 8) =
        *(const bf16x8*)(vt + d * 72 + slot * 8);
  }
}

// ---------------- flash attention: 128 q-rows/block, 8 waves, dbuf K/V ----------------
__global__ __launch_bounds__(512) void attn_fwd(const u16* __restrict__ Qb, const u16* __restrict__ Kb,
                                                const u16* __restrict__ Vtb, u16* __restrict__ ctx) {
  __shared__ u16 Ks[2][64 * 128];    // [buf][t][k] 256B rows, XOR-swizzled
  __shared__ u16 Vts[2][128 * 64];   // [buf][d][t] 128B rows, XOR-swizzled
  __shared__ u16 Ps[8 * 16 * 64];    // per-wave P tile, XOR-swizzled
  const int tid = threadIdx.x;
  const int lane = tid & 63;
  const int w = tid >> 6;            // 0..7
  const int q0 = blockIdx.x * 128;
  const int head = blockIdx.y;
  const int rl = lane & 15, cg = lane >> 4;

  bf16x8 qf[4];
  {
    const u16* Qrow = Qb + ((size_t)head * SQ + q0 + w * 16 + rl) * HD;
#pragma unroll
    for (int kk = 0; kk < 4; ++kk)
      qf[kk] = *(const bf16x8*)(Qrow + kk * 32 + cg * 8);
  }

  f32x4 acc[8];
#pragma unroll
  for (int i = 0; i < 8; ++i) acc[i] = (f32x4){0.f, 0.f, 0.f, 0.f};
  float mrow[4] = {-3.0e38f, -3.0e38f, -3.0e38f, -3.0e38f};
  float lrow[4] = {0.f, 0.f, 0.f, 0.f};

  const int ntile = (MEML + q0 + 128) >> 6;   // 18..32

  auto stageKV = [&](int it) {
    int t0 = it * 64;
    int buf = it & 1;
#pragma unroll
    for (int i = 0; i < 2; ++i) {
      int flat = i * 512 + tid;
      int row = flat >> 4;
      int scb = ((flat & 15) << 4) ^ ((row & 7) << 4);
      gload_lds16((const char*)(Kb + ((size_t)head * KV + t0 + row) * HD) + scb,
                  (char*)Ks[buf] + (flat << 4));
    }
#pragma unroll
    for (int i = 0; i < 2; ++i) {
      int flat = i * 512 + tid;
      int row = flat >> 3;
      int scb = ((flat & 7) << 4) ^ ((row & 7) << 4);
      gload_lds16((const char*)(Vtb + ((size_t)head * HD + row) * KV + t0) + scb,
                  (char*)Vts[buf] + (flat << 4));
    }
  };

  stageKV(0);

  for (int it = 0; it < ntile; ++it) {
    const int t0 = it * 64;
    if (it + 1 < ntile) {
      stageKV(it + 1);
      asm volatile("s_waitcnt vmcnt(4)" ::: "memory");   // tile it landed; it+1 in flight
    } else {
      asm volatile("s_waitcnt vmcnt(0)" ::: "memory");
    }
    __builtin_amdgcn_s_barrier();
    const char* Kbuf = (const char*)Ks[it & 1];
    const char* Vbuf = (const char*)Vts[it & 1];
    const bool live = (t0 - MEML) <= (q0 + w * 16 + 15);
    if (live) {
      f32x4 sf[4];
#pragma unroll
      for (int tn = 0; tn < 4; ++tn) {
        f32x4 s = (f32x4){0.f, 0.f, 0.f, 0.f};
#pragma unroll
        for (int kk = 0; kk < 4; ++kk) {
          int row = tn * 16 + rl;
          int cb = (kk * 64 + cg * 16) ^ ((row & 7) << 4);
          bf16x8 kf = *(const bf16x8*)(Kbuf + row * 256 + cb);
          s = __builtin_amdgcn_mfma_f32_16x16x32_bf16(qf[kk], kf, s, 0, 0, 0);
        }
        sf[tn] = s;
      }
      if (t0 + 63 > MEML + q0 + w * 16) {
#pragma unroll
        for (int tn = 0; tn < 4; ++tn)
#pragma unroll
          for (int j = 0; j < 4; ++j) {
            int t = t0 + tn * 16 + rl;
            int srowq = q0 + w * 16 + cg * 4 + j;
            if (t - MEML > srowq) sf[tn][j] = -40000.0f;
          }
      }
      float mt[4];
#pragma unroll
      for (int j = 0; j < 4; ++j)
        mt[j] = fmaxf(fmaxf(sf[0][j], sf[1][j]), fmaxf(sf[2][j], sf[3][j]));
#pragma unroll
      for (int off = 1; off <= 8; off <<= 1)
#pragma unroll
        for (int j = 0; j < 4; ++j) mt[j] = fmaxf(mt[j], __shfl_xor(mt[j], off, 64));
      float pscale[4];
#pragma unroll
      for (int j = 0; j < 4; ++j) {
        float mn = fmaxf(mrow[j], mt[j]);
        pscale[j] = __expf(mrow[j] - mn);
        mrow[j] = mn;
      }
      float lsum[4] = {0.f, 0.f, 0.f, 0.f};
#pragma unroll
      for (int tn = 0; tn < 4; ++tn)
#pragma unroll
        for (int j = 0; j < 4; ++j) {
          float p = __expf(sf[tn][j] - mrow[j]);
          lsum[j] += p;
          int prow = cg * 4 + j;
          int colb = (tn * 16 + rl) * 2;
          int addr = w * 2048 + prow * 128 + (colb ^ ((prow & 7) << 4));
          *(u16*)((char*)Ps + addr) = f32_to_bf16(p);
        }
#pragma unroll
      for (int off = 1; off <= 8; off <<= 1)
#pragma unroll
        for (int j = 0; j < 4; ++j) lsum[j] += __shfl_xor(lsum[j], off, 64);
#pragma unroll
      for (int j = 0; j < 4; ++j) lrow[j] = lrow[j] * pscale[j] + lsum[j];
#pragma unroll
      for (int dn = 0; dn < 8; ++dn)
#pragma unroll
        for (int j = 0; j < 4; ++j) acc[dn][j] *= pscale[j];
#pragma unroll
      for (int dn = 0; dn < 8; ++dn) {
#pragma unroll
        for (int kk2 = 0; kk2 < 2; ++kk2) {
          int pcb = (kk2 * 64 + cg * 16) ^ ((rl & 7) << 4);
          bf16x8 pf = *(const bf16x8*)((const char*)Ps + w * 2048 + rl * 128 + pcb);
          int vrow = dn * 16 + rl;
          int vcb = (kk2 * 64 + cg * 16) ^ ((vrow & 7) << 4);
          bf16x8 vf = *(const bf16x8*)(Vbuf + vrow * 128 + vcb);
          acc[dn] = __builtin_amdgcn_mfma_f32_16x16x32_bf16(pf, vf, acc[dn], 0, 0, 0);
        }
      }
    }
    __builtin_amdgcn_s_barrier();   // all reads of buf[it&1] done before it+2 overwrites
  }

  const int b = head >> 5, nh = head & 31;
#pragma unroll
  for (int dn = 0; dn < 8; ++dn)
#pragma unroll
    for (int j = 0; j < 4; ++j) {
      int srowq = q0 + w * 16 + cg * 4 + j;
      float v = acc[dn][j] / lrow[j];
      ctx[((size_t)(srowq * 2 + b)) * H + (size_t)nh * HD + dn * 16 + rl] = f32_to_bf16(v);
    }
}

// ---------------- launch ----------------
extern "C" void kernel_launch(void* const* d_in, const int* in_sizes, int n_in,
                              void* d_out, int out_size, void* d_ws, size_t ws_size,
                              hipStream_t stream) {
  const float* hidden  = (const float*)d_in[0];
  const float* mem     = (const float*)d_in[3];
  const float* qkv_w   = (const float*)d_in[4];
  const float* qkv_b   = (const float*)d_in[5];
  const float* dense_w = (const float*)d_in[6];
  const float* dense_b = (const float*)d_in[7];
  float* out = (float*)d_out;
  char* ws = (char*)d_ws;

  u16* mixed = (u16*)ws;                          // 50,331,648 B used (2048x12288 bf16)
  char* R1 = ws + 100663296;
  u16* hid_bf = (u16*)R1;                         // aliased: pre-GEMM1 use
  u16* Qb  = (u16*)R1;
  u16* Kb  = (u16*)(R1 + 16777216);
  u16* Vtb = (u16*)(R1 + 50331648);
  u16* ctx = (u16*)(R1 + 83886080);
  float* cost = (float*)(ws + 234881024);
  float* sint = (float*)(ws + 234881024 + 262144);

  conv_bf16<<<8192, 256, 0, stream>>>(hidden, hid_bf, 2097152);
  rope_tables<<<256, 256, 0, stream>>>(cost, sint);
  gemm3p<<<dim3(64, 8), 512, 0, stream>>>(hid_bf, qkv_w, qkv_b, mixed, 12288, 4096);
  prep_qk<<<dim3(16, 64), 256, 0, stream>>>(mixed, cost, sint, Qb, Kb);
  prep_kv<<<dim3(32, 64), 256, 0, stream>>>(mixed, mem, Kb, Vtb);
  attn_fwd<<<dim3(8, 64), 512, 0, stream>>>(Qb, Kb, Vtb, ctx);
  gemm2p<<<dim3(32, 8), 512, 0, stream>>>(ctx, dense_w, dense_b, out, 4096, 4096);
}

// Round 11
// 544.453 us; speedup vs baseline: 1.1418x; 1.1418x over previous
//
#include <hip/hip_runtime.h>

// SelfAttention (Transformer-XL style) on gfx950.
// conv2 (hidden+qkv_w fused), gemmT NF=3 (qkv), conv(dense_w) AFTER gemm1 (aliases
// qw_bf tail!), vectorized RoPE preps, flash attn (128-row dbuf), gemmT NF=2.

typedef __attribute__((ext_vector_type(4))) float f32x4;
typedef __attribute__((ext_vector_type(8))) short bf16x8;
typedef unsigned short u16;

#define SQ   1024
#define BSZ  2
#define H    4096
#define NH   32
#define HD   128
#define MEML 1024
#define KV   2048

__device__ __forceinline__ u16 f32_to_bf16(float f) {
  union { float f; unsigned int u; } v; v.f = f;
  unsigned int r = v.u + 0x7FFFu + ((v.u >> 16) & 1u);
  return (u16)(r >> 16);
}
__device__ __forceinline__ float bf16_to_f32(u16 x) {
  union { unsigned int u; float f; } v; v.u = ((unsigned int)x) << 16; return v.f;
}

__device__ __forceinline__ void gload_lds16(const void* g, void* l) {
  __builtin_amdgcn_global_load_lds((const __attribute__((address_space(1))) void*)g,
                                   (__attribute__((address_space(3))) void*)l, 16, 0, 0);
}

// ---------------- f32 -> bf16 convert (single buffer) ----------------
__global__ __launch_bounds__(256) void conv_bf16(const float* __restrict__ in,
                                                 u16* __restrict__ out, int n4) {
  int idx = blockIdx.x * 256 + threadIdx.x;
  if (idx < n4) {
    float4 v = ((const float4*)in)[idx];
    ushort4 o;
    o.x = f32_to_bf16(v.x); o.y = f32_to_bf16(v.y);
    o.z = f32_to_bf16(v.z); o.w = f32_to_bf16(v.w);
    ((ushort4*)out)[idx] = o;
  }
}

// ---------------- fused f32 -> bf16 convert (hidden + qkv_w only) ----------------
// NOTE: dense_w is NOT fused here — dw_bf aliases the tail of qw_bf, so its
// conversion must run AFTER gemm1 consumes qw_bf (r10 failure root cause).
#define NA4 2097152
#define NB4 12582912
__global__ __launch_bounds__(256) void conv2(const float* __restrict__ a, u16* __restrict__ oa,
                                             const float* __restrict__ bsrc, u16* __restrict__ ob) {
  int idx = blockIdx.x * 256 + threadIdx.x;
  const float* s; u16* o; int off;
  if (idx < NA4) { s = a;    o = oa; off = idx; }
  else           { s = bsrc; o = ob; off = idx - NA4; }
  float4 v = ((const float4*)s)[off];
  ushort4 r;
  r.x = f32_to_bf16(v.x); r.y = f32_to_bf16(v.y);
  r.z = f32_to_bf16(v.z); r.w = f32_to_bf16(v.w);
  ((ushort4*)o)[off] = r;
}

// ---------------- RoPE tables ----------------
__global__ __launch_bounds__(256) void rope_tables(float* __restrict__ cost, float* __restrict__ sint) {
  int idx = blockIdx.x * 256 + threadIdx.x;   // 65536 = 1024 s * 64 j
  int s = idx >> 6, j = idx & 63;
  float inv = powf(10000.0f, -(float)j / 64.0f);
  float ang = (float)(MEML + s) * inv;
  cost[idx] = cosf(ang);
  sint[idx] = sinf(ang);
}

// ---------------- GEMM: C[M,N] = A[M,K](bf16) * B[N,K]^T(bf16) + bias[N] ----------
// BM=256, BN=NF*64, BK=64; 512 threads = 8 waves (2M x 4N), per-wave 128 x NF*16.
// 4 phases/K-tile; 8KiB stage units; counted vmcnt(NF) once per tile. (r5 measured best)
template <typename OUT_T, int NF>
__global__ __launch_bounds__(512, 2) void gemmT(const u16* __restrict__ A, const u16* __restrict__ B,
                                                const float* __restrict__ bias, OUT_T* __restrict__ C,
                                                int N, int K) {
  constexpr int WN = NF * 16;                 // per-wave N width
  constexpr int NH0 = (NF + 1) / 2;           // frags in set0
  constexpr int SB2 = NF - (NF >> 1);         // B units staged at ph2
  __shared__ char lds[2][32768 + NF * 8192];  // A rows 0..255 @0, B rows @32768
  const int tid = threadIdx.x;
  const int lane = tid & 63;
  const int w = tid >> 6;
  const int wm = w >> 2, wn = w & 3;
  const int rl = lane & 15, cg = lane >> 4;
  const int m0 = blockIdx.y * 256, n0 = blockIdx.x * (NF * 64);
  const int nt = K >> 6;

  const int srow = tid >> 3;                              // 0..63 (unit-local row)
  const int scb = ((tid & 7) << 4) ^ ((srow & 7) << 4);   // pre-swizzled source byte col

  auto stage_a = [&](int tile, int ua) {
    if (tile >= nt) return;
    gload_lds16((const char*)(A + (size_t)(m0 + ua * 64 + srow) * K + (size_t)tile * 64) + scb,
                lds[tile & 1] + ua * 8192 + tid * 16);
  };
  auto stage_b = [&](int tile, int ub) {
    if (tile >= nt) return;
    gload_lds16((const char*)(B + (size_t)(n0 + ub * 64 + srow) * K + (size_t)tile * 64) + scb,
                lds[tile & 1] + 32768 + ub * 8192 + tid * 16);
  };

  f32x4 acc[8][NF];
#pragma unroll
  for (int i = 0; i < 8; ++i)
#pragma unroll
    for (int j = 0; j < NF; ++j) acc[i][j] = (f32x4){0.f, 0.f, 0.f, 0.f};

  bf16x8 af[4][2], bf[NF][2];

  auto read_a = [&](const char* buf, int mh) {
#pragma unroll
    for (int mi = 0; mi < 4; ++mi) {
      int R = wm * 128 + mh * 64 + mi * 16 + rl;
#pragma unroll
      for (int kk = 0; kk < 2; ++kk) {
        int cb = (kk * 64 + cg * 16) ^ ((R & 7) << 4);
        af[mi][kk] = *(const bf16x8*)(buf + R * 128 + cb);
      }
    }
  };
  auto read_b1 = [&](const char* buf, int nl) {
    int R = wn * WN + nl * 16 + rl;
#pragma unroll
    for (int kk = 0; kk < 2; ++kk) {
      int cb = (kk * 64 + cg * 16) ^ ((R & 7) << 4);
      bf[nl][kk] = *(const bf16x8*)(buf + 32768 + R * 128 + cb);
    }
  };
  auto mfset = [&](int mh, int lo, int hi) {
    __builtin_amdgcn_s_setprio(1);
#pragma unroll
    for (int kk = 0; kk < 2; ++kk)
#pragma unroll
      for (int mi = 0; mi < 4; ++mi)
#pragma unroll
        for (int nl = 0; nl < NF; ++nl)
          if (nl >= lo && nl < hi)
            acc[mh * 4 + mi][nl] = __builtin_amdgcn_mfma_f32_16x16x32_bf16(
                af[mi][kk], bf[nl][kk], acc[mh * 4 + mi][nl], 0, 0, 0);
    __builtin_amdgcn_s_setprio(0);
  };

  // prologue: tile0 A+B, tile1 B; wait tile0 landed (tile1.B = NF outstanding)
#pragma unroll
  for (int ua = 0; ua < 4; ++ua) stage_a(0, ua);
#pragma unroll
  for (int ub = 0; ub < NF; ++ub) stage_b(0, ub);
#pragma unroll
  for (int ub = 0; ub < NF; ++ub) stage_b(1, ub);
  if (NF == 2)      { asm volatile("s_waitcnt vmcnt(2)" ::: "memory"); }
  else if (NF == 3) { asm volatile("s_waitcnt vmcnt(3)" ::: "memory"); }
  else              { asm volatile("s_waitcnt vmcnt(4)" ::: "memory"); }
  __builtin_amdgcn_s_barrier();

  for (int kt = 0; kt < nt; ++kt) {
    const char* buf = lds[kt & 1];
    // ph0: quadrant (mh0,set0); stage (kt+1).A units 0,1 -> p^1
    read_a(buf, 0);
#pragma unroll
    for (int nl = 0; nl < NH0; ++nl) read_b1(buf, nl);
    stage_a(kt + 1, 0); stage_a(kt + 1, 1);
    __builtin_amdgcn_s_barrier();
    asm volatile("s_waitcnt lgkmcnt(0)" ::: "memory");
    mfset(0, 0, NH0);
    __builtin_amdgcn_s_barrier();
    // ph1: quadrant (mh0,set1); stage (kt+1).A units 2,3 -> p^1
#pragma unroll
    for (int nl = NH0; nl < NF; ++nl) read_b1(buf, nl);
    stage_a(kt + 1, 2); stage_a(kt + 1, 3);
    __builtin_amdgcn_s_barrier();
    asm volatile("s_waitcnt lgkmcnt(0)" ::: "memory");
    mfset(0, NH0, NF);
    __builtin_amdgcn_s_barrier();
    // ph2: quadrant (mh1,set1); stage (kt+2).B units 0..SB2-1 -> p
    read_a(buf, 1);
#pragma unroll
    for (int ub = 0; ub < SB2; ++ub) stage_b(kt + 2, ub);
    __builtin_amdgcn_s_barrier();
    asm volatile("s_waitcnt lgkmcnt(0)" ::: "memory");
    mfset(1, NH0, NF);
    __builtin_amdgcn_s_barrier();
    // ph3: quadrant (mh1,set0); stage (kt+2).B units SB2..NF-1 -> p; counted vmcnt
#pragma unroll
    for (int ub = SB2; ub < NF; ++ub) stage_b(kt + 2, ub);
    __builtin_amdgcn_s_barrier();
    mfset(1, 0, NH0);
    if (kt + 2 < nt) {
      if (NF == 2)      { asm volatile("s_waitcnt vmcnt(2)" ::: "memory"); }
      else if (NF == 3) { asm volatile("s_waitcnt vmcnt(3)" ::: "memory"); }
      else              { asm volatile("s_waitcnt vmcnt(4)" ::: "memory"); }
    } else if (kt + 1 < nt) {
      asm volatile("s_waitcnt vmcnt(0)" ::: "memory");
    }
    __builtin_amdgcn_s_barrier();
  }

  // epilogue: C layout col=lane&15, row=(lane>>4)*4+j
#pragma unroll
  for (int ni = 0; ni < NF; ++ni) {
    int col = n0 + wn * WN + ni * 16 + rl;
    float bv = bias[col];
#pragma unroll
    for (int mi = 0; mi < 8; ++mi) {
      int rbase = m0 + wm * 128 + mi * 16 + cg * 4;
#pragma unroll
      for (int j = 0; j < 4; ++j) {
        float v = acc[mi][ni][j] + bv;
        if constexpr (sizeof(OUT_T) == 2)
          C[(size_t)(rbase + j) * N + col] = (OUT_T)f32_to_bf16(v);
        else
          C[(size_t)(rbase + j) * N + col] = (OUT_T)v;
      }
    }
  }
}

// ---------------- prep: roped Q (scaled) and roped new-K (vectorized) ----------
__global__ __launch_bounds__(256) void prep_qk(const u16* __restrict__ mixed,
                                               const float* __restrict__ cost,
                                               const float* __restrict__ sint,
                                               u16* __restrict__ Qb, u16* __restrict__ Kb) {
  int s0 = blockIdx.x * 64, head = blockIdx.y;
  int b = head >> 5, nh = head & 31;
  int tid = threadIdx.x;
  const float qs = 0.08838834764831845f;  // 1/sqrt(128)
#pragma unroll
  for (int i = 0; i < 4; ++i) {
    int flat = i * 256 + tid;           // 1024 = 64 s * 16 j-groups
    int sl = flat >> 4, jg = (flat & 15) << 2;
    int s = s0 + sl;
    size_t base = ((size_t)(s * 2 + b)) * 12288 + (size_t)nh * 384;
    ushort4 q1v = *(const ushort4*)(mixed + base + jg);
    ushort4 q2v = *(const ushort4*)(mixed + base + 64 + jg);
    ushort4 k1v = *(const ushort4*)(mixed + base + 128 + jg);
    ushort4 k2v = *(const ushort4*)(mixed + base + 192 + jg);
    float4 cv = *(const float4*)(cost + s * 64 + jg);
    float4 sv = *(const float4*)(sint + s * 64 + jg);
    const u16* q1a = (const u16*)&q1v; const u16* q2a = (const u16*)&q2v;
    const u16* k1a = (const u16*)&k1v; const u16* k2a = (const u16*)&k2v;
    const float* ca = (const float*)&cv; const float* sa = (const float*)&sv;
    ushort4 qo1, qo2, ko1, ko2;
    u16* qo1a = (u16*)&qo1; u16* qo2a = (u16*)&qo2;
    u16* ko1a = (u16*)&ko1; u16* ko2a = (u16*)&ko2;
#pragma unroll
    for (int e = 0; e < 4; ++e) {
      float q1 = bf16_to_f32(q1a[e]), q2 = bf16_to_f32(q2a[e]);
      float k1 = bf16_to_f32(k1a[e]), k2 = bf16_to_f32(k2a[e]);
      float c = ca[e], sn = sa[e];
      qo1a[e] = f32_to_bf16((q1 * c - q2 * sn) * qs);
      qo2a[e] = f32_to_bf16((q2 * c + q1 * sn) * qs);
      ko1a[e] = f32_to_bf16(k1 * c - k2 * sn);
      ko2a[e] = f32_to_bf16(k2 * c + k1 * sn);
    }
    size_t qoff = ((size_t)head * SQ + s) * HD;
    *(ushort4*)(Qb + qoff + jg)      = qo1;
    *(ushort4*)(Qb + qoff + 64 + jg) = qo2;
    size_t koff = ((size_t)head * KV + MEML + s) * HD;
    *(ushort4*)(Kb + koff + jg)      = ko1;
    *(ushort4*)(Kb + koff + 64 + jg) = ko2;
  }
}

// ---------------- prep: mem-K copy + V transposed per head (vectorized) ----------------
__global__ __launch_bounds__(256) void prep_kv(const u16* __restrict__ mixed,
                                               const float* __restrict__ mem,
                                               u16* __restrict__ Kb, u16* __restrict__ Vtb) {
  int t0 = blockIdx.x * 64, head = blockIdx.y;
  int b = head >> 5, nh = head & 31;
  __shared__ u16 vt[128 * 72];
  int tid = threadIdx.x;
  if (t0 < MEML) {
#pragma unroll
    for (int i = 0; i < 8; ++i) {       // 2048 = 64 t * 32 d-groups
      int flat = i * 256 + tid;
      int tl = flat >> 5, dg = (flat & 31) << 2;
      float4 kv4 = *(const float4*)(mem + ((size_t)b * MEML + t0 + tl) * 8192 + (size_t)nh * HD + dg);
      ushort4 o;
      o.x = f32_to_bf16(kv4.x); o.y = f32_to_bf16(kv4.y);
      o.z = f32_to_bf16(kv4.z); o.w = f32_to_bf16(kv4.w);
      *(ushort4*)(Kb + ((size_t)head * KV + t0 + tl) * HD + dg) = o;
    }
  }
#pragma unroll
  for (int i = 0; i < 8; ++i) {
    int flat = i * 256 + tid;
    int tl = flat >> 5, dg = (flat & 31) << 2;
    int t = t0 + tl;
    u16 e0, e1, e2, e3;
    if (t < MEML) {
      float4 v4 = *(const float4*)(mem + ((size_t)b * MEML + t) * 8192 + 4096 + (size_t)nh * HD + dg);
      e0 = f32_to_bf16(v4.x); e1 = f32_to_bf16(v4.y);
      e2 = f32_to_bf16(v4.z); e3 = f32_to_bf16(v4.w);
    } else {
      ushort4 v4 = *(const ushort4*)(mixed + ((size_t)((t - MEML) * 2 + b)) * 12288 + (size_t)nh * 384 + 256 + dg);
      e0 = v4.x; e1 = v4.y; e2 = v4.z; e3 = v4.w;
    }
    vt[(dg + 0) * 72 + tl] = e0;
    vt[(dg + 1) * 72 + tl] = e1;
    vt[(dg + 2) * 72 + tl] = e2;
    vt[(dg + 3) * 72 + tl] = e3;
  }
  __syncthreads();
#pragma unroll
  for (int i = 0; i < 4; ++i) {
    int c = i * 256 + tid;
    int d = c >> 3, slot = c & 7;
    *(bf16x8*)(Vtb + ((size_t)head * HD + d) * KV + t0 + slot * 8) =
        *(const bf16x8*)(vt + d * 72 + slot * 8);
  }
}

// ---------------- flash attention: 128 q-rows/block, 8 waves, dbuf K/V ----------------
__global__ __launch_bounds__(512) void attn_fwd(const u16* __restrict__ Qb, const u16* __restrict__ Kb,
                                                const u16* __restrict__ Vtb, u16* __restrict__ ctx) {
  __shared__ u16 Ks[2][64 * 128];    // [buf][t][k] 256B rows, XOR-swizzled
  __shared__ u16 Vts[2][128 * 64];   // [buf][d][t] 128B rows, XOR-swizzled
  __shared__ u16 Ps[8 * 16 * 64];    // per-wave P tile, XOR-swizzled
  const int tid = threadIdx.x;
  const int lane = tid & 63;
  const int w = tid >> 6;            // 0..7
  const int q0 = blockIdx.x * 128;
  const int head = blockIdx.y;
  const int rl = lane & 15, cg = lane >> 4;

  bf16x8 qf[4];
  {
    const u16* Qrow = Qb + ((size_t)head * SQ + q0 + w * 16 + rl) * HD;
#pragma unroll
    for (int kk = 0; kk < 4; ++kk)
      qf[kk] = *(const bf16x8*)(Qrow + kk * 32 + cg * 8);
  }

  f32x4 acc[8];
#pragma unroll
  for (int i = 0; i < 8; ++i) acc[i] = (f32x4){0.f, 0.f, 0.f, 0.f};
  float mrow[4] = {-3.0e38f, -3.0e38f, -3.0e38f, -3.0e38f};
  float lrow[4] = {0.f, 0.f, 0.f, 0.f};

  const int ntile = (MEML + q0 + 128) >> 6;   // 18..32

  auto stageKV = [&](int it) {
    int t0 = it * 64;
    int buf = it & 1;
#pragma unroll
    for (int i = 0; i < 2; ++i) {
      int flat = i * 512 + tid;
      int row = flat >> 4;
      int scb = ((flat & 15) << 4) ^ ((row & 7) << 4);
      gload_lds16((const char*)(Kb + ((size_t)head * KV + t0 + row) * HD) + scb,
                  (char*)Ks[buf] + (flat << 4));
    }
#pragma unroll
    for (int i = 0; i < 2; ++i) {
      int flat = i * 512 + tid;
      int row = flat >> 3;
      int scb = ((flat & 7) << 4) ^ ((row & 7) << 4);
      gload_lds16((const char*)(Vtb + ((size_t)head * HD + row) * KV + t0) + scb,
                  (char*)Vts[buf] + (flat << 4));
    }
  };

  stageKV(0);

  for (int it = 0; it < ntile; ++it) {
    const int t0 = it * 64;
    if (it + 1 < ntile) {
      stageKV(it + 1);
      asm volatile("s_waitcnt vmcnt(4)" ::: "memory");   // tile it landed; it+1 in flight
    } else {
      asm volatile("s_waitcnt vmcnt(0)" ::: "memory");
    }
    __builtin_amdgcn_s_barrier();
    const char* Kbuf = (const char*)Ks[it & 1];
    const char* Vbuf = (const char*)Vts[it & 1];
    const bool live = (t0 - MEML) <= (q0 + w * 16 + 15);
    if (live) {
      f32x4 sf[4];
#pragma unroll
      for (int tn = 0; tn < 4; ++tn) {
        f32x4 s = (f32x4){0.f, 0.f, 0.f, 0.f};
#pragma unroll
        for (int kk = 0; kk < 4; ++kk) {
          int row = tn * 16 + rl;
          int cb = (kk * 64 + cg * 16) ^ ((row & 7) << 4);
          bf16x8 kf = *(const bf16x8*)(Kbuf + row * 256 + cb);
          s = __builtin_amdgcn_mfma_f32_16x16x32_bf16(qf[kk], kf, s, 0, 0, 0);
        }
        sf[tn] = s;
      }
      if (t0 + 63 > MEML + q0 + w * 16) {
#pragma unroll
        for (int tn = 0; tn < 4; ++tn)
#pragma unroll
          for (int j = 0; j < 4; ++j) {
            int t = t0 + tn * 16 + rl;
            int srowq = q0 + w * 16 + cg * 4 + j;
            if (t - MEML > srowq) sf[tn][j] = -40000.0f;
          }
      }
      float mt[4];
#pragma unroll
      for (int j = 0; j < 4; ++j)
        mt[j] = fmaxf(fmaxf(sf[0][j], sf[1][j]), fmaxf(sf[2][j], sf[3][j]));
#pragma unroll
      for (int off = 1; off <= 8; off <<= 1)
#pragma unroll
        for (int j = 0; j < 4; ++j) mt[j] = fmaxf(mt[j], __shfl_xor(mt[j], off, 64));
      float pscale[4];
#pragma unroll
      for (int j = 0; j < 4; ++j) {
        float mn = fmaxf(mrow[j], mt[j]);
        pscale[j] = __expf(mrow[j] - mn);
        mrow[j] = mn;
      }
      float lsum[4] = {0.f, 0.f, 0.f, 0.f};
#pragma unroll
      for (int tn = 0; tn < 4; ++tn)
#pragma unroll
        for (int j = 0; j < 4; ++j) {
          float p = __expf(sf[tn][j] - mrow[j]);
          lsum[j] += p;
          int prow = cg * 4 + j;
          int colb = (tn * 16 + rl) * 2;
          int addr = w * 2048 + prow * 128 + (colb ^ ((prow & 7) << 4));
          *(u16*)((char*)Ps + addr) = f32_to_bf16(p);
        }
#pragma unroll
      for (int off = 1; off <= 8; off <<= 1)
#pragma unroll
        for (int j = 0; j < 4; ++j) lsum[j] += __shfl_xor(lsum[j], off, 64);
#pragma unroll
      for (int j = 0; j < 4; ++j) lrow[j] = lrow[j] * pscale[j] + lsum[j];
#pragma unroll
      for (int dn = 0; dn < 8; ++dn)
#pragma unroll
        for (int j = 0; j < 4; ++j) acc[dn][j] *= pscale[j];
#pragma unroll
      for (int dn = 0; dn < 8; ++dn) {
#pragma unroll
        for (int kk2 = 0; kk2 < 2; ++kk2) {
          int pcb = (kk2 * 64 + cg * 16) ^ ((rl & 7) << 4);
          bf16x8 pf = *(const bf16x8*)((const char*)Ps + w * 2048 + rl * 128 + pcb);
          int vrow = dn * 16 + rl;
          int vcb = (kk2 * 64 + cg * 16) ^ ((vrow & 7) << 4);
          bf16x8 vf = *(const bf16x8*)(Vbuf + vrow * 128 + vcb);
          acc[dn] = __builtin_amdgcn_mfma_f32_16x16x32_bf16(pf, vf, acc[dn], 0, 0, 0);
        }
      }
    }
    __builtin_amdgcn_s_barrier();   // all reads of buf[it&1] done before it+2 overwrites
  }

  const int b = head >> 5, nh = head & 31;
#pragma unroll
  for (int dn = 0; dn < 8; ++dn)
#pragma unroll
    for (int j = 0; j < 4; ++j) {
      int srowq = q0 + w * 16 + cg * 4 + j;
      float v = acc[dn][j] / lrow[j];
      ctx[((size_t)(srowq * 2 + b)) * H + (size_t)nh * HD + dn * 16 + rl] = f32_to_bf16(v);
    }
}

// ---------------- launch ----------------
extern "C" void kernel_launch(void* const* d_in, const int* in_sizes, int n_in,
                              void* d_out, int out_size, void* d_ws, size_t ws_size,
                              hipStream_t stream) {
  const float* hidden  = (const float*)d_in[0];
  const float* mem     = (const float*)d_in[3];
  const float* qkv_w   = (const float*)d_in[4];
  const float* qkv_b   = (const float*)d_in[5];
  const float* dense_w = (const float*)d_in[6];
  const float* dense_b = (const float*)d_in[7];
  float* out = (float*)d_out;
  char* ws = (char*)d_ws;

  u16* mixed = (u16*)ws;                          // 50,331,648 B used (2048x12288 bf16)
  char* R1 = ws + 100663296;
  u16* hid_bf = (u16*)R1;                         // aliased: pre-GEMM1 use
  u16* qw_bf  = (u16*)(R1 + 16777216);            // 100 MB; consumed by gemm1
  u16* Qb  = (u16*)R1;
  u16* Kb  = (u16*)(R1 + 16777216);
  u16* Vtb = (u16*)(R1 + 50331648);
  u16* ctx = (u16*)(R1 + 83886080);
  u16* dw_bf = (u16*)(R1 + 100663296);            // overlaps qw_bf tail -> convert AFTER gemm1
  float* cost = (float*)(ws + 234881024);
  float* sint = (float*)(ws + 234881024 + 262144);

  conv2<<<57344, 256, 0, stream>>>(hidden, hid_bf, qkv_w, qw_bf);
  rope_tables<<<256, 256, 0, stream>>>(cost, sint);
  gemmT<u16, 3><<<dim3(64, 8), 512, 0, stream>>>(hid_bf, qw_bf, qkv_b, mixed, 12288, 4096);
  conv_bf16<<<16384, 256, 0, stream>>>(dense_w, dw_bf, 4194304);   // after gemm1 (alias!)
  prep_qk<<<dim3(16, 64), 256, 0, stream>>>(mixed, cost, sint, Qb, Kb);
  prep_kv<<<dim3(32, 64), 256, 0, stream>>>(mixed, mem, Kb, Vtb);
  attn_fwd<<<dim3(8, 64), 512, 0, stream>>>(Qb, Kb, Vtb, ctx);
  gemmT<float, 2><<<dim3(32, 8), 512, 0, stream>>>(ctx, dw_bf, dense_b, out, 4096, 4096);
}

// Round 13
// 487.520 us; speedup vs baseline: 1.2752x; 1.1168x over previous
//
#include <hip/hip_runtime.h>

// SelfAttention (Transformer-XL style) on gfx950.
// conv2 (hidden+qkv_w fused), gemmT NF=3 (qkv), conv(dense_w) AFTER gemm1 (alias),
// vectorized RoPE preps, flash attn (SWAPPED-QK: lane-local softmax, 2-shfl
// reductions, packed P writes, LDS-transpose epilogue), gemmT NF=2 (dense).
// r13 = r12 with epilogue copy bug fixed (covered only d 0..63; now full 0..127).

typedef __attribute__((ext_vector_type(4))) float f32x4;
typedef __attribute__((ext_vector_type(8))) short bf16x8;
typedef unsigned short u16;

#define SQ   1024
#define BSZ  2
#define H    4096
#define NH   32
#define HD   128
#define MEML 1024
#define KV   2048

__device__ __forceinline__ u16 f32_to_bf16(float f) {
  union { float f; unsigned int u; } v; v.f = f;
  unsigned int r = v.u + 0x7FFFu + ((v.u >> 16) & 1u);
  return (u16)(r >> 16);
}
__device__ __forceinline__ float bf16_to_f32(u16 x) {
  union { unsigned int u; float f; } v; v.u = ((unsigned int)x) << 16; return v.f;
}

__device__ __forceinline__ void gload_lds16(const void* g, void* l) {
  __builtin_amdgcn_global_load_lds((const __attribute__((address_space(1))) void*)g,
                                   (__attribute__((address_space(3))) void*)l, 16, 0, 0);
}

// ---------------- f32 -> bf16 convert (single buffer) ----------------
__global__ __launch_bounds__(256) void conv_bf16(const float* __restrict__ in,
                                                 u16* __restrict__ out, int n4) {
  int idx = blockIdx.x * 256 + threadIdx.x;
  if (idx < n4) {
    float4 v = ((const float4*)in)[idx];
    ushort4 o;
    o.x = f32_to_bf16(v.x); o.y = f32_to_bf16(v.y);
    o.z = f32_to_bf16(v.z); o.w = f32_to_bf16(v.w);
    ((ushort4*)out)[idx] = o;
  }
}

// ---------------- fused f32 -> bf16 convert (hidden + qkv_w only) ----------------
#define NA4 2097152
#define NB4 12582912
__global__ __launch_bounds__(256) void conv2(const float* __restrict__ a, u16* __restrict__ oa,
                                             const float* __restrict__ bsrc, u16* __restrict__ ob) {
  int idx = blockIdx.x * 256 + threadIdx.x;
  const float* s; u16* o; int off;
  if (idx < NA4) { s = a;    o = oa; off = idx; }
  else           { s = bsrc; o = ob; off = idx - NA4; }
  float4 v = ((const float4*)s)[off];
  ushort4 r;
  r.x = f32_to_bf16(v.x); r.y = f32_to_bf16(v.y);
  r.z = f32_to_bf16(v.z); r.w = f32_to_bf16(v.w);
  ((ushort4*)o)[off] = r;
}

// ---------------- RoPE tables ----------------
__global__ __launch_bounds__(256) void rope_tables(float* __restrict__ cost, float* __restrict__ sint) {
  int idx = blockIdx.x * 256 + threadIdx.x;   // 65536 = 1024 s * 64 j
  int s = idx >> 6, j = idx & 63;
  float inv = powf(10000.0f, -(float)j / 64.0f);
  float ang = (float)(MEML + s) * inv;
  cost[idx] = cosf(ang);
  sint[idx] = sinf(ang);
}

// ---------------- GEMM: C[M,N] = A[M,K](bf16) * B[N,K]^T(bf16) + bias[N] ----------
// BM=256, BN=NF*64, BK=64; 512 threads = 8 waves (2M x 4N), per-wave 128 x NF*16.
template <typename OUT_T, int NF>
__global__ __launch_bounds__(512, 2) void gemmT(const u16* __restrict__ A, const u16* __restrict__ B,
                                                const float* __restrict__ bias, OUT_T* __restrict__ C,
                                                int N, int K) {
  constexpr int WN = NF * 16;                 // per-wave N width
  constexpr int NH0 = (NF + 1) / 2;           // frags in set0
  constexpr int SB2 = NF - (NF >> 1);         // B units staged at ph2
  __shared__ char lds[2][32768 + NF * 8192];  // A rows 0..255 @0, B rows @32768
  const int tid = threadIdx.x;
  const int lane = tid & 63;
  const int w = tid >> 6;
  const int wm = w >> 2, wn = w & 3;
  const int rl = lane & 15, cg = lane >> 4;
  const int m0 = blockIdx.y * 256, n0 = blockIdx.x * (NF * 64);
  const int nt = K >> 6;

  const int srow = tid >> 3;                              // 0..63 (unit-local row)
  const int scb = ((tid & 7) << 4) ^ ((srow & 7) << 4);   // pre-swizzled source byte col

  auto stage_a = [&](int tile, int ua) {
    if (tile >= nt) return;
    gload_lds16((const char*)(A + (size_t)(m0 + ua * 64 + srow) * K + (size_t)tile * 64) + scb,
                lds[tile & 1] + ua * 8192 + tid * 16);
  };
  auto stage_b = [&](int tile, int ub) {
    if (tile >= nt) return;
    gload_lds16((const char*)(B + (size_t)(n0 + ub * 64 + srow) * K + (size_t)tile * 64) + scb,
                lds[tile & 1] + 32768 + ub * 8192 + tid * 16);
  };

  f32x4 acc[8][NF];
#pragma unroll
  for (int i = 0; i < 8; ++i)
#pragma unroll
    for (int j = 0; j < NF; ++j) acc[i][j] = (f32x4){0.f, 0.f, 0.f, 0.f};

  bf16x8 af[4][2], bf[NF][2];

  auto read_a = [&](const char* buf, int mh) {
#pragma unroll
    for (int mi = 0; mi < 4; ++mi) {
      int R = wm * 128 + mh * 64 + mi * 16 + rl;
#pragma unroll
      for (int kk = 0; kk < 2; ++kk) {
        int cb = (kk * 64 + cg * 16) ^ ((R & 7) << 4);
        af[mi][kk] = *(const bf16x8*)(buf + R * 128 + cb);
      }
    }
  };
  auto read_b1 = [&](const char* buf, int nl) {
    int R = wn * WN + nl * 16 + rl;
#pragma unroll
    for (int kk = 0; kk < 2; ++kk) {
      int cb = (kk * 64 + cg * 16) ^ ((R & 7) << 4);
      bf[nl][kk] = *(const bf16x8*)(buf + 32768 + R * 128 + cb);
    }
  };
  auto mfset = [&](int mh, int lo, int hi) {
    __builtin_amdgcn_s_setprio(1);
#pragma unroll
    for (int kk = 0; kk < 2; ++kk)
#pragma unroll
      for (int mi = 0; mi < 4; ++mi)
#pragma unroll
        for (int nl = 0; nl < NF; ++nl)
          if (nl >= lo && nl < hi)
            acc[mh * 4 + mi][nl] = __builtin_amdgcn_mfma_f32_16x16x32_bf16(
                af[mi][kk], bf[nl][kk], acc[mh * 4 + mi][nl], 0, 0, 0);
    __builtin_amdgcn_s_setprio(0);
  };

  // prologue: tile0 A+B, tile1 B; wait tile0 landed (tile1.B = NF outstanding)
#pragma unroll
  for (int ua = 0; ua < 4; ++ua) stage_a(0, ua);
#pragma unroll
  for (int ub = 0; ub < NF; ++ub) stage_b(0, ub);
#pragma unroll
  for (int ub = 0; ub < NF; ++ub) stage_b(1, ub);
  if (NF == 2)      { asm volatile("s_waitcnt vmcnt(2)" ::: "memory"); }
  else if (NF == 3) { asm volatile("s_waitcnt vmcnt(3)" ::: "memory"); }
  else              { asm volatile("s_waitcnt vmcnt(4)" ::: "memory"); }
  __builtin_amdgcn_s_barrier();

  for (int kt = 0; kt < nt; ++kt) {
    const char* buf = lds[kt & 1];
    // ph0: quadrant (mh0,set0); stage (kt+1).A units 0,1 -> p^1
    read_a(buf, 0);
#pragma unroll
    for (int nl = 0; nl < NH0; ++nl) read_b1(buf, nl);
    stage_a(kt + 1, 0); stage_a(kt + 1, 1);
    __builtin_amdgcn_s_barrier();
    asm volatile("s_waitcnt lgkmcnt(0)" ::: "memory");
    mfset(0, 0, NH0);
    __builtin_amdgcn_s_barrier();
    // ph1: quadrant (mh0,set1); stage (kt+1).A units 2,3 -> p^1
#pragma unroll
    for (int nl = NH0; nl < NF; ++nl) read_b1(buf, nl);
    stage_a(kt + 1, 2); stage_a(kt + 1, 3);
    __builtin_amdgcn_s_barrier();
    asm volatile("s_waitcnt lgkmcnt(0)" ::: "memory");
    mfset(0, NH0, NF);
    __builtin_amdgcn_s_barrier();
    // ph2: quadrant (mh1,set1); stage (kt+2).B units 0..SB2-1 -> p
    read_a(buf, 1);
#pragma unroll
    for (int ub = 0; ub < SB2; ++ub) stage_b(kt + 2, ub);
    __builtin_amdgcn_s_barrier();
    asm volatile("s_waitcnt lgkmcnt(0)" ::: "memory");
    mfset(1, NH0, NF);
    __builtin_amdgcn_s_barrier();
    // ph3: quadrant (mh1,set0); stage (kt+2).B units SB2..NF-1 -> p; counted vmcnt
#pragma unroll
    for (int ub = SB2; ub < NF; ++ub) stage_b(kt + 2, ub);
    __builtin_amdgcn_s_barrier();
    mfset(1, 0, NH0);
    if (kt + 2 < nt) {
      if (NF == 2)      { asm volatile("s_waitcnt vmcnt(2)" ::: "memory"); }
      else if (NF == 3) { asm volatile("s_waitcnt vmcnt(3)" ::: "memory"); }
      else              { asm volatile("s_waitcnt vmcnt(4)" ::: "memory"); }
    } else if (kt + 1 < nt) {
      asm volatile("s_waitcnt vmcnt(0)" ::: "memory");
    }
    __builtin_amdgcn_s_barrier();
  }

  // epilogue: C layout col=lane&15, row=(lane>>4)*4+j
#pragma unroll
  for (int ni = 0; ni < NF; ++ni) {
    int col = n0 + wn * WN + ni * 16 + rl;
    float bv = bias[col];
#pragma unroll
    for (int mi = 0; mi < 8; ++mi) {
      int rbase = m0 + wm * 128 + mi * 16 + cg * 4;
#pragma unroll
      for (int j = 0; j < 4; ++j) {
        float v = acc[mi][ni][j] + bv;
        if constexpr (sizeof(OUT_T) == 2)
          C[(size_t)(rbase + j) * N + col] = (OUT_T)f32_to_bf16(v);
        else
          C[(size_t)(rbase + j) * N + col] = (OUT_T)v;
      }
    }
  }
}

// ---------------- prep: roped Q (scaled) and roped new-K (vectorized) ----------
__global__ __launch_bounds__(256) void prep_qk(const u16* __restrict__ mixed,
                                               const float* __restrict__ cost,
                                               const float* __restrict__ sint,
                                               u16* __restrict__ Qb, u16* __restrict__ Kb) {
  int s0 = blockIdx.x * 64, head = blockIdx.y;
  int b = head >> 5, nh = head & 31;
  int tid = threadIdx.x;
  const float qs = 0.08838834764831845f;  // 1/sqrt(128)
#pragma unroll
  for (int i = 0; i < 4; ++i) {
    int flat = i * 256 + tid;           // 1024 = 64 s * 16 j-groups
    int sl = flat >> 4, jg = (flat & 15) << 2;
    int s = s0 + sl;
    size_t base = ((size_t)(s * 2 + b)) * 12288 + (size_t)nh * 384;
    ushort4 q1v = *(const ushort4*)(mixed + base + jg);
    ushort4 q2v = *(const ushort4*)(mixed + base + 64 + jg);
    ushort4 k1v = *(const ushort4*)(mixed + base + 128 + jg);
    ushort4 k2v = *(const ushort4*)(mixed + base + 192 + jg);
    float4 cv = *(const float4*)(cost + s * 64 + jg);
    float4 sv = *(const float4*)(sint + s * 64 + jg);
    const u16* q1a = (const u16*)&q1v; const u16* q2a = (const u16*)&q2v;
    const u16* k1a = (const u16*)&k1v; const u16* k2a = (const u16*)&k2v;
    const float* ca = (const float*)&cv; const float* sa = (const float*)&sv;
    ushort4 qo1, qo2, ko1, ko2;
    u16* qo1a = (u16*)&qo1; u16* qo2a = (u16*)&qo2;
    u16* ko1a = (u16*)&ko1; u16* ko2a = (u16*)&ko2;
#pragma unroll
    for (int e = 0; e < 4; ++e) {
      float q1 = bf16_to_f32(q1a[e]), q2 = bf16_to_f32(q2a[e]);
      float k1 = bf16_to_f32(k1a[e]), k2 = bf16_to_f32(k2a[e]);
      float c = ca[e], sn = sa[e];
      qo1a[e] = f32_to_bf16((q1 * c - q2 * sn) * qs);
      qo2a[e] = f32_to_bf16((q2 * c + q1 * sn) * qs);
      ko1a[e] = f32_to_bf16(k1 * c - k2 * sn);
      ko2a[e] = f32_to_bf16(k2 * c + k1 * sn);
    }
    size_t qoff = ((size_t)head * SQ + s) * HD;
    *(ushort4*)(Qb + qoff + jg)      = qo1;
    *(ushort4*)(Qb + qoff + 64 + jg) = qo2;
    size_t koff = ((size_t)head * KV + MEML + s) * HD;
    *(ushort4*)(Kb + koff + jg)      = ko1;
    *(ushort4*)(Kb + koff + 64 + jg) = ko2;
  }
}

// ---------------- prep: mem-K copy + V transposed per head (vectorized) ----------------
__global__ __launch_bounds__(256) void prep_kv(const u16* __restrict__ mixed,
                                               const float* __restrict__ mem,
                                               u16* __restrict__ Kb, u16* __restrict__ Vtb) {
  int t0 = blockIdx.x * 64, head = blockIdx.y;
  int b = head >> 5, nh = head & 31;
  __shared__ u16 vt[128 * 72];
  int tid = threadIdx.x;
  if (t0 < MEML) {
#pragma unroll
    for (int i = 0; i < 8; ++i) {       // 2048 = 64 t * 32 d-groups
      int flat = i * 256 + tid;
      int tl = flat >> 5, dg = (flat & 31) << 2;
      float4 kv4 = *(const float4*)(mem + ((size_t)b * MEML + t0 + tl) * 8192 + (size_t)nh * HD + dg);
      ushort4 o;
      o.x = f32_to_bf16(kv4.x); o.y = f32_to_bf16(kv4.y);
      o.z = f32_to_bf16(kv4.z); o.w = f32_to_bf16(kv4.w);
      *(ushort4*)(Kb + ((size_t)head * KV + t0 + tl) * HD + dg) = o;
    }
  }
#pragma unroll
  for (int i = 0; i < 8; ++i) {
    int flat = i * 256 + tid;
    int tl = flat >> 5, dg = (flat & 31) << 2;
    int t = t0 + tl;
    u16 e0, e1, e2, e3;
    if (t < MEML) {
      float4 v4 = *(const float4*)(mem + ((size_t)b * MEML + t) * 8192 + 4096 + (size_t)nh * HD + dg);
      e0 = f32_to_bf16(v4.x); e1 = f32_to_bf16(v4.y);
      e2 = f32_to_bf16(v4.z); e3 = f32_to_bf16(v4.w);
    } else {
      ushort4 v4 = *(const ushort4*)(mixed + ((size_t)((t - MEML) * 2 + b)) * 12288 + (size_t)nh * 384 + 256 + dg);
      e0 = v4.x; e1 = v4.y; e2 = v4.z; e3 = v4.w;
    }
    vt[(dg + 0) * 72 + tl] = e0;
    vt[(dg + 1) * 72 + tl] = e1;
    vt[(dg + 2) * 72 + tl] = e2;
    vt[(dg + 3) * 72 + tl] = e3;
  }
  __syncthreads();
#pragma unroll
  for (int i = 0; i < 4; ++i) {
    int c = i * 256 + tid;
    int d = c >> 3, slot = c & 7;
    *(bf16x8*)(Vtb + ((size_t)head * HD + d) * KV + t0 + slot * 8) =
        *(const bf16x8*)(vt + d * 72 + slot * 8);
  }
}

// ---------------- flash attention: SWAPPED-QK, lane-local softmax ----------------
// sf = mfma(kf, qf) -> S^T[t = tn*16+cg*4+j][s = rl]; acc = mfma(vf, pf) ->
// ctx^T[d = dn*16+cg*4+j][s = rl]. All fragment loads identical to r11.
__global__ __launch_bounds__(512) void attn_fwd(const u16* __restrict__ Qb, const u16* __restrict__ Kb,
                                                const u16* __restrict__ Vtb, u16* __restrict__ ctx) {
  __shared__ u16 Ks[2][64 * 128];    // [buf][t][k]; reused as T[128][128] in epilogue
  __shared__ u16 Vts[2][128 * 64];   // [buf][d][t]
  __shared__ u16 Ps[8 * 16 * 64];    // per-wave P: [s=rl row][t], XOR-swizzled
  const int tid = threadIdx.x;
  const int lane = tid & 63;
  const int w = tid >> 6;            // 0..7
  const int q0 = blockIdx.x * 128;
  const int head = blockIdx.y;
  const int rl = lane & 15, cg = lane >> 4;
  const int sglob = q0 + w * 16 + rl;   // this lane's query row

  bf16x8 qf[4];
  {
    const u16* Qrow = Qb + ((size_t)head * SQ + sglob) * HD;
#pragma unroll
    for (int kk = 0; kk < 4; ++kk)
      qf[kk] = *(const bf16x8*)(Qrow + kk * 32 + cg * 8);
  }

  f32x4 acc[8];
#pragma unroll
  for (int i = 0; i < 8; ++i) acc[i] = (f32x4){0.f, 0.f, 0.f, 0.f};
  float mrow = -3.0e38f;
  float lrow = 0.f;

  const int ntile = (MEML + q0 + 128) >> 6;   // 18..32

  auto stageKV = [&](int it) {
    int t0 = it * 64;
    int buf = it & 1;
#pragma unroll
    for (int i = 0; i < 2; ++i) {
      int flat = i * 512 + tid;
      int row = flat >> 4;
      int scb = ((flat & 15) << 4) ^ ((row & 7) << 4);
      gload_lds16((const char*)(Kb + ((size_t)head * KV + t0 + row) * HD) + scb,
                  (char*)Ks[buf] + (flat << 4));
    }
#pragma unroll
    for (int i = 0; i < 2; ++i) {
      int flat = i * 512 + tid;
      int row = flat >> 3;
      int scb = ((flat & 7) << 4) ^ ((row & 7) << 4);
      gload_lds16((const char*)(Vtb + ((size_t)head * HD + row) * KV + t0) + scb,
                  (char*)Vts[buf] + (flat << 4));
    }
  };

  stageKV(0);

  for (int it = 0; it < ntile; ++it) {
    const int t0 = it * 64;
    if (it + 1 < ntile) {
      stageKV(it + 1);
      asm volatile("s_waitcnt vmcnt(4)" ::: "memory");
    } else {
      asm volatile("s_waitcnt vmcnt(0)" ::: "memory");
    }
    __builtin_amdgcn_s_barrier();
    const char* Kbuf = (const char*)Ks[it & 1];
    const char* Vbuf = (const char*)Vts[it & 1];
    const bool live = (t0 - MEML) <= (q0 + w * 16 + 15);
    if (live) {
      // S^T = K Q^T : lane holds S[t=t0+tn*16+cg*4+j][s=sglob]
      f32x4 sf[4];
#pragma unroll
      for (int tn = 0; tn < 4; ++tn) {
        f32x4 s = (f32x4){0.f, 0.f, 0.f, 0.f};
#pragma unroll
        for (int kk = 0; kk < 4; ++kk) {
          int row = tn * 16 + rl;
          int cb = (kk * 64 + cg * 16) ^ ((row & 7) << 4);
          bf16x8 kf = *(const bf16x8*)(Kbuf + row * 256 + cb);
          s = __builtin_amdgcn_mfma_f32_16x16x32_bf16(kf, qf[kk], s, 0, 0, 0);
        }
        sf[tn] = s;
      }
      if (t0 + 63 > MEML + q0 + w * 16) {
#pragma unroll
        for (int tn = 0; tn < 4; ++tn)
#pragma unroll
          for (int j = 0; j < 4; ++j) {
            int t = t0 + tn * 16 + cg * 4 + j;
            if (t - MEML > sglob) sf[tn][j] = -40000.0f;
          }
      }
      // in-lane max over 16 t-values, then 2-shfl allreduce across cg
      float mt = sf[0][0];
#pragma unroll
      for (int tn = 0; tn < 4; ++tn)
#pragma unroll
        for (int j = 0; j < 4; ++j) mt = fmaxf(mt, sf[tn][j]);
      mt = fmaxf(mt, __shfl_xor(mt, 16, 64));
      mt = fmaxf(mt, __shfl_xor(mt, 32, 64));
      float mn = fmaxf(mrow, mt);
      float psc = __expf(mrow - mn);
      mrow = mn;
      float ls = 0.f;
#pragma unroll
      for (int tn = 0; tn < 4; ++tn) {
        ushort4 pk;
        u16* pka = (u16*)&pk;
#pragma unroll
        for (int j = 0; j < 4; ++j) {
          float p = __expf(sf[tn][j] - mn);
          ls += p;
          pka[j] = f32_to_bf16(p);
        }
        int addr = w * 2048 + rl * 128 + ((tn * 32 + cg * 8) ^ ((rl & 7) << 4));
        *(ushort4*)((char*)Ps + addr) = pk;
      }
      ls += __shfl_xor(ls, 16, 64);
      ls += __shfl_xor(ls, 32, 64);
      lrow = lrow * psc + ls;
#pragma unroll
      for (int dn = 0; dn < 8; ++dn)
#pragma unroll
        for (int j = 0; j < 4; ++j) acc[dn][j] *= psc;
      // ctx^T += V^T P^T : A=Vt rows=d, B=P rows(s)=rl
#pragma unroll
      for (int dn = 0; dn < 8; ++dn) {
#pragma unroll
        for (int kk2 = 0; kk2 < 2; ++kk2) {
          int pcb = (kk2 * 64 + cg * 16) ^ ((rl & 7) << 4);
          bf16x8 pf = *(const bf16x8*)((const char*)Ps + w * 2048 + rl * 128 + pcb);
          int vrow = dn * 16 + rl;
          int vcb = (kk2 * 64 + cg * 16) ^ ((vrow & 7) << 4);
          bf16x8 vf = *(const bf16x8*)(Vbuf + vrow * 128 + vcb);
          acc[dn] = __builtin_amdgcn_mfma_f32_16x16x32_bf16(vf, pf, acc[dn], 0, 0, 0);
        }
      }
    }
    __builtin_amdgcn_s_barrier();
  }

  // epilogue: acc holds ctx^T[d][s] -> transpose via LDS (reuse Ks, 32 KB) for
  // coalesced 16B global stores. T layout: [128 s-local][128 d] bf16, 256B rows.
  const float inv = 1.0f / lrow;
  u16* T = (u16*)Ks;
  {
    int trow = w * 16 + rl;           // trow&7 == rl&7
#pragma unroll
    for (int dn = 0; dn < 8; ++dn) {
      ushort4 pk;
      u16* pka = (u16*)&pk;
#pragma unroll
      for (int j = 0; j < 4; ++j) pka[j] = f32_to_bf16(acc[dn][j] * inv);
      int addr = trow * 256 + ((dn * 32 + cg * 8) ^ ((rl & 7) << 4));
      *(ushort4*)((char*)T + addr) = pk;
    }
  }
  asm volatile("s_waitcnt lgkmcnt(0)" ::: "memory");
  __builtin_amdgcn_s_barrier();
  const int b = head >> 5, nh = head & 31;
#pragma unroll
  for (int i = 0; i < 4; ++i) {
    int flat = i * 512 + tid;         // 2048 chunks of 16B (128 rows x 16 chunks)
    int r = flat >> 4, c = flat & 15;
    bf16x8 v = *(const bf16x8*)((const char*)T + r * 256 + ((c * 16) ^ ((r & 7) << 4)));
    *(bf16x8*)(ctx + ((size_t)((q0 + r) * 2 + b)) * H + (size_t)nh * HD + c * 8) = v;
  }
}

// ---------------- launch ----------------
extern "C" void kernel_launch(void* const* d_in, const int* in_sizes, int n_in,
                              void* d_out, int out_size, void* d_ws, size_t ws_size,
                              hipStream_t stream) {
  const float* hidden  = (const float*)d_in[0];
  const float* mem     = (const float*)d_in[3];
  const float* qkv_w   = (const float*)d_in[4];
  const float* qkv_b   = (const float*)d_in[5];
  const float* dense_w = (const float*)d_in[6];
  const float* dense_b = (const float*)d_in[7];
  float* out = (float*)d_out;
  char* ws = (char*)d_ws;

  u16* mixed = (u16*)ws;                          // 50,331,648 B used (2048x12288 bf16)
  char* R1 = ws + 100663296;
  u16* hid_bf = (u16*)R1;                         // aliased: pre-GEMM1 use
  u16* qw_bf  = (u16*)(R1 + 16777216);            // 100 MB; consumed by gemm1
  u16* Qb  = (u16*)R1;
  u16* Kb  = (u16*)(R1 + 16777216);
  u16* Vtb = (u16*)(R1 + 50331648);
  u16* ctx = (u16*)(R1 + 83886080);
  u16* dw_bf = (u16*)(R1 + 100663296);            // overlaps qw_bf tail -> convert AFTER gemm1
  float* cost = (float*)(ws + 234881024);
  float* sint = (float*)(ws + 234881024 + 262144);

  conv2<<<57344, 256, 0, stream>>>(hidden, hid_bf, qkv_w, qw_bf);
  rope_tables<<<256, 256, 0, stream>>>(cost, sint);
  gemmT<u16, 3><<<dim3(64, 8), 512, 0, stream>>>(hid_bf, qw_bf, qkv_b, mixed, 12288, 4096);
  conv_bf16<<<16384, 256, 0, stream>>>(dense_w, dw_bf, 4194304);   // after gemm1 (alias!)
  prep_qk<<<dim3(16, 64), 256, 0, stream>>>(mixed, cost, sint, Qb, Kb);
  prep_kv<<<dim3(32, 64), 256, 0, stream>>>(mixed, mem, Kb, Vtb);
  attn_fwd<<<dim3(8, 64), 512, 0, stream>>>(Qb, Kb, Vtb, ctx);
  gemmT<float, 2><<<dim3(32, 8), 512, 0, stream>>>(ctx, dw_bf, dense_b, out, 4096, 4096);
}